// Round 1
// baseline (1104.429 us; speedup 1.0000x reference)
//
#include <hip/hip_runtime.h>
#include <hip/hip_bf16.h>

// ---------------------------------------------------------------------------
// ArcFace PartialFC loss, fused:
//   k1: normalize embeddings -> f32 copy (exact target path) + bf16 copy (GEMM)
//   k2: streaming GEMM  S[c,b] = W[c,:]·Ê[b,:]  (bf16 MFMA, f32 accum),
//       fused ||w_c||^2 accumulation, fused exp(64*cos-64) partial sums,
//       atomicAdd into per-column gsum[512]. W is read exactly once (410 MB).
//   k3: exact-f32 target cosine per row, arcface margin, swap target term,
//       per-row NLL -> atomic sum + valid count
//   k4: loss = nll_sum / max(count,1)
// ---------------------------------------------------------------------------

#define D_SZ 512
#define B_SZ 512
#define C_SZ 200000
#define BM   64          // C-rows per block in k2; 200000/64 = 3125 exactly
#define SCL  64.0f
#define MRG  0.5f

typedef __attribute__((ext_vector_type(8))) short  bf16x8;
typedef __attribute__((ext_vector_type(8))) __bf16 bf16x8f;
typedef __attribute__((ext_vector_type(4))) float  f32x4;

__device__ __forceinline__ ushort f2bf_bits(float x) {
  __bf16 h = (__bf16)x;
  return __builtin_bit_cast(ushort, h);
}

__device__ __forceinline__ bf16x8 cvt8(float4 a, float4 b) {
  bf16x8f t;
  t[0] = (__bf16)a.x; t[1] = (__bf16)a.y; t[2] = (__bf16)a.z; t[3] = (__bf16)a.w;
  t[4] = (__bf16)b.x; t[5] = (__bf16)b.y; t[6] = (__bf16)b.z; t[7] = (__bf16)b.w;
  return __builtin_bit_cast(bf16x8, t);
}

// --- k1: row-normalize embeddings. 512 blocks x 64 threads (1 wave = 1 row).
__global__ void k_norm_emb(const float* __restrict__ emb,
                           float* __restrict__ nf32,
                           ushort* __restrict__ nbf) {
  const int row  = blockIdx.x;
  const int lane = threadIdx.x;               // 0..63
  const float4* r4 = (const float4*)(emb + (size_t)row * D_SZ);
  float4 a = r4[lane];                        // d = lane*4      (0..255)
  float4 b = r4[lane + 64];                   // d = 256+lane*4  (256..511)
  float ss = a.x*a.x + a.y*a.y + a.z*a.z + a.w*a.w
           + b.x*b.x + b.y*b.y + b.z*b.z + b.w*b.w;
#pragma unroll
  for (int off = 32; off; off >>= 1) ss += __shfl_xor(ss, off, 64);
  const float s = 1.0f / fmaxf(sqrtf(ss), 1e-12f);
  a.x *= s; a.y *= s; a.z *= s; a.w *= s;
  b.x *= s; b.y *= s; b.z *= s; b.w *= s;
  float4* o4 = (float4*)(nf32 + (size_t)row * D_SZ);
  o4[lane] = a; o4[lane + 64] = b;
  ushort4 ua, ub;
  ua.x = f2bf_bits(a.x); ua.y = f2bf_bits(a.y); ua.z = f2bf_bits(a.z); ua.w = f2bf_bits(a.w);
  ub.x = f2bf_bits(b.x); ub.y = f2bf_bits(b.y); ub.z = f2bf_bits(b.z); ub.w = f2bf_bits(b.w);
  ushort4* ob = (ushort4*)(nbf + (size_t)row * D_SZ);
  ob[lane] = ua; ob[lane + 64] = ub;
}

// --- k2: the streaming GEMM + fused softmax-denominator partials.
// grid 3125 blocks x 512 threads. Wave w owns B-cols [64w, 64w+64).
// Per wave: 4 C-frags x 4 B-frags of 16x16x32 MFMA, K-loop of 16 steps.
__global__ __launch_bounds__(512)
void k_gemm_lse(const float* __restrict__ W,
                const ushort* __restrict__ E,
                float* __restrict__ gsum) {
  __shared__ float wlds[BM];                  // ||w||^2 for this block's rows
  const int tid  = threadIdx.x;
  const int wave = tid >> 6;
  const int lane = tid & 63;
  const int l15  = lane & 15;                 // A: row, B: col, D: col
  const int lk   = lane >> 4;                 // k-group 0..3
  const size_t c0 = (size_t)blockIdx.x * BM;

  const float*  wbase = W + (c0 + l15) * D_SZ + lk * 8;
  const ushort* ebase = E + (size_t)(wave * 64 + l15) * D_SZ + lk * 8;

  f32x4 acc[4][4];
  const f32x4 z = {0.f, 0.f, 0.f, 0.f};
#pragma unroll
  for (int ci = 0; ci < 4; ++ci)
#pragma unroll
    for (int bi = 0; bi < 4; ++bi) acc[ci][bi] = z;
  float wn[4] = {0.f, 0.f, 0.f, 0.f};

#pragma unroll 2
  for (int ks = 0; ks < 16; ++ks) {
    const int k0 = ks * 32;
    bf16x8 wf[4], ef[4];
#pragma unroll
    for (int ci = 0; ci < 4; ++ci) {
      const float* p = wbase + (size_t)(ci * 16) * D_SZ + k0;
      float4 x0 = *(const float4*)p;
      float4 x1 = *(const float4*)(p + 4);
      wn[ci] += x0.x*x0.x + x0.y*x0.y + x0.z*x0.z + x0.w*x0.w
              + x1.x*x1.x + x1.y*x1.y + x1.z*x1.z + x1.w*x1.w;
      wf[ci] = cvt8(x0, x1);
    }
#pragma unroll
    for (int bi = 0; bi < 4; ++bi)
      ef[bi] = *(const bf16x8*)(ebase + (size_t)(bi * 16) * D_SZ + k0);
#pragma unroll
    for (int ci = 0; ci < 4; ++ci)
#pragma unroll
      for (int bi = 0; bi < 4; ++bi)
        acc[ci][bi] = __builtin_amdgcn_mfma_f32_16x16x32_bf16(
            wf[ci], ef[bi], acc[ci][bi], 0, 0, 0);
  }

  // full ||w||^2 per row: butterfly over the 4 k-groups (lane bits 4,5)
#pragma unroll
  for (int ci = 0; ci < 4; ++ci) {
    wn[ci] += __shfl_xor(wn[ci], 16, 64);
    wn[ci] += __shfl_xor(wn[ci], 32, 64);
  }
  if (wave == 0 && lane < 16) {
#pragma unroll
    for (int ci = 0; ci < 4; ++ci) wlds[ci * 16 + l15] = wn[ci];
  }
  __syncthreads();

  // epilogue: cos -> exp(64*cos-64), sum over this block's 64 C-rows per col
  float psum[4] = {0.f, 0.f, 0.f, 0.f};
#pragma unroll
  for (int ci = 0; ci < 4; ++ci) {
#pragma unroll
    for (int r = 0; r < 4; ++r) {
      const float n2  = wlds[ci * 16 + lk * 4 + r];   // row = ci*16+lk*4+r
      const float inv = 1.0f / fmaxf(sqrtf(n2), 1e-12f);
#pragma unroll
      for (int bi = 0; bi < 4; ++bi) {
        float c = acc[ci][bi][r] * inv;
        c = fminf(fmaxf(c, -1.0f), 1.0f);
        psum[bi] += __expf(fmaf(SCL, c, -SCL));
      }
    }
  }
#pragma unroll
  for (int bi = 0; bi < 4; ++bi) {
    psum[bi] += __shfl_xor(psum[bi], 16, 64);
    psum[bi] += __shfl_xor(psum[bi], 32, 64);
  }
  if (lk == 0) {
#pragma unroll
    for (int bi = 0; bi < 4; ++bi)
      atomicAdd(&gsum[wave * 64 + bi * 16 + l15], psum[bi]);
  }
}

// --- k3: exact f32 target logit + margin + per-row NLL.
// grid 64 blocks x 512 threads; wave handles row b = blockIdx*8 + wave.
__global__ void k_target(const float* __restrict__ W,
                         const float* __restrict__ nf32,
                         const int* __restrict__ labels,
                         const float* __restrict__ gsum,
                         float* __restrict__ nll) {   // nll[0]=sum, nll[1]=count
  const int wave = threadIdx.x >> 6;
  const int lane = threadIdx.x & 63;
  const int b = blockIdx.x * 8 + wave;
  const int lab = labels[b];
  const bool valid = (lab >= 0);
  const int slab = valid ? lab : 0;
  const float* wr = W    + (size_t)slab * D_SZ;
  const float* er = nf32 + (size_t)b    * D_SZ;
  float dot = 0.f, wn2 = 0.f;
#pragma unroll
  for (int i = 0; i < 2; ++i) {
    const int d = i * 256 + lane * 4;
    float4 w4 = *(const float4*)(wr + d);
    float4 e4 = *(const float4*)(er + d);
    dot += w4.x*e4.x + w4.y*e4.y + w4.z*e4.z + w4.w*e4.w;
    wn2 += w4.x*w4.x + w4.y*w4.y + w4.z*w4.z + w4.w*w4.w;
  }
#pragma unroll
  for (int off = 32; off; off >>= 1) {
    dot += __shfl_xor(dot, off, 64);
    wn2 += __shfl_xor(wn2, off, 64);
  }
  if (lane == 0 && valid) {
    const float inv  = 1.0f / fmaxf(sqrtf(wn2), 1e-12f);
    float cost = fminf(fmaxf(dot * inv, -1.0f), 1.0f);      // clamped cosine
    const float th   = acosf(fminf(fmaxf(cost, -1.0f + 1e-7f), 1.0f - 1e-7f));
    const float newt = cosf(th + MRG);
    // swap target term in the fixed-shift (max=64) denominator
    const float sum  = gsum[b] - expf(fmaf(SCL, cost, -SCL))
                               + expf(fmaf(SCL, newt, -SCL));
    const float lse  = logf(sum) + SCL;
    atomicAdd(&nll[0], lse - SCL * newt);
    atomicAdd(&nll[1], 1.0f);
  }
}

__global__ void k_final(const float* __restrict__ nll, float* __restrict__ out) {
  out[0] = nll[0] / fmaxf(nll[1], 1.0f);
}

// ---------------------------------------------------------------------------
extern "C" void kernel_launch(void* const* d_in, const int* in_sizes, int n_in,
                              void* d_out, int out_size, void* d_ws, size_t ws_size,
                              hipStream_t stream) {
  const float* emb    = (const float*)d_in[0];
  const int*   labels = (const int*)  d_in[1];
  const float* W      = (const float*)d_in[2];
  float* out = (float*)d_out;

  // ws layout: [0,1MB) norm_emb f32 | [1MB,1.5MB) norm_emb bf16
  //            | gsum[512] | nll[2]
  char* ws = (char*)d_ws;
  float*  nf32 = (float*)ws;
  ushort* nbf  = (ushort*)(ws + (1u << 20));
  float*  gsum = (float*)(ws + (1u << 20) + (1u << 19));
  float*  nll  = gsum + B_SZ;

  hipMemsetAsync(gsum, 0, (B_SZ + 2) * sizeof(float), stream);
  k_norm_emb<<<B_SZ, 64, 0, stream>>>(emb, nf32, nbf);
  k_gemm_lse<<<C_SZ / BM, 512, 0, stream>>>(W, nbf, gsum);
  k_target<<<B_SZ / 8, 512, 0, stream>>>(W, nf32, labels, gsum, nll);
  k_final<<<1, 1, 0, stream>>>(nll, out);
}

// Round 2
// 700.091 us; speedup vs baseline: 1.5776x; 1.5776x over previous
//
#include <hip/hip_runtime.h>
#include <hip/hip_bf16.h>

// ---------------------------------------------------------------------------
// ArcFace PartialFC loss, fused:
//   k1: normalize embeddings -> f32 copy (exact target path) + bf16 copy (GEMM)
//   k2: LDS-staged streaming GEMM  S[c,b] = W[c,:]·Ê[b,:]:
//       per block: load 64x512 f32 W-tile ONCE (coalesced), cvt->bf16 into
//       XOR-swizzled LDS, fused ||w||^2; then barrier-free ds_read+MFMA
//       K-loop; epilogue exp(64*cos-64) partials -> atomicAdd gsum[512].
//   k3: exact-f32 target cosine per row, arcface margin, swap target term,
//       per-row NLL -> atomic sum + valid count
//   k4: loss = nll_sum / max(count,1)
// ---------------------------------------------------------------------------

#define D_SZ 512
#define B_SZ 512
#define C_SZ 200000
#define BM   64          // C-rows per block in k2; 200000/64 = 3125 exactly
#define SCL  64.0f
#define MRG  0.5f

typedef __attribute__((ext_vector_type(8))) short  bf16x8;
typedef __attribute__((ext_vector_type(8))) __bf16 bf16x8f;
typedef __attribute__((ext_vector_type(4))) float  f32x4;

__device__ __forceinline__ ushort f2bf_bits(float x) {
  __bf16 h = (__bf16)x;
  return __builtin_bit_cast(ushort, h);
}

__device__ __forceinline__ bf16x8 cvt8(float4 a, float4 b) {
  bf16x8f t;
  t[0] = (__bf16)a.x; t[1] = (__bf16)a.y; t[2] = (__bf16)a.z; t[3] = (__bf16)a.w;
  t[4] = (__bf16)b.x; t[5] = (__bf16)b.y; t[6] = (__bf16)b.z; t[7] = (__bf16)b.w;
  return __builtin_bit_cast(bf16x8, t);
}

// --- k1: row-normalize embeddings. 128 blocks x 256 threads (1 wave = 1 row).
__global__ void k_norm_emb(const float* __restrict__ emb,
                           float* __restrict__ nf32,
                           ushort* __restrict__ nbf) {
  const int row  = blockIdx.x * 4 + (threadIdx.x >> 6);
  const int lane = threadIdx.x & 63;
  const float4* r4 = (const float4*)(emb + (size_t)row * D_SZ);
  float4 a = r4[lane];                        // d = lane*4      (0..255)
  float4 b = r4[lane + 64];                   // d = 256+lane*4  (256..511)
  float ss = a.x*a.x + a.y*a.y + a.z*a.z + a.w*a.w
           + b.x*b.x + b.y*b.y + b.z*b.z + b.w*b.w;
#pragma unroll
  for (int off = 32; off; off >>= 1) ss += __shfl_xor(ss, off, 64);
  const float s = 1.0f / fmaxf(sqrtf(ss), 1e-12f);
  a.x *= s; a.y *= s; a.z *= s; a.w *= s;
  b.x *= s; b.y *= s; b.z *= s; b.w *= s;
  float4* o4 = (float4*)(nf32 + (size_t)row * D_SZ);
  o4[lane] = a; o4[lane + 64] = b;
  ushort4 ua, ub;
  ua.x = f2bf_bits(a.x); ua.y = f2bf_bits(a.y); ua.z = f2bf_bits(a.z); ua.w = f2bf_bits(a.w);
  ub.x = f2bf_bits(b.x); ub.y = f2bf_bits(b.y); ub.z = f2bf_bits(b.z); ub.w = f2bf_bits(b.w);
  ushort4* ob = (ushort4*)(nbf + (size_t)row * D_SZ);
  ob[lane] = ua; ob[lane + 64] = ub;
}

// --- k2: LDS-staged GEMM + fused softmax-denominator partials.
// grid 3125 blocks x 512 threads. Wave w owns B-cols [64w, 64w+64).
// Stage: 64x512 f32 -> bf16 LDS tile (XOR swizzle (row&7)<<4), ||w||^2 fused.
// Compute: 16 K-steps x (4 ds_read_b128 A + 4 global B + 16 MFMA), no barrier.
__global__ __launch_bounds__(512, 4)   // cap 128 VGPR -> 2 blocks/CU (overlap)
void k_gemm_lse(const float* __restrict__ W,
                const ushort* __restrict__ E,
                float* __restrict__ gsum) {
  __shared__ ushort wtile[BM * D_SZ];         // 64 KiB, swizzled bf16 tile
  __shared__ float  wlds[BM];                 // ||w||^2 per row
  const int tid  = threadIdx.x;
  const int wave = tid >> 6;
  const int lane = tid & 63;
  const size_t c0 = (size_t)blockIdx.x * BM;

  // ---- stage phase: row r = tid>>3, 8 threads/row (j = tid&7), 64 f32 each
  {
    const int r = tid >> 3, j = tid & 7;
    const float* wr = W + (c0 + r) * (size_t)D_SZ;
    char* wrow = (char*)wtile + r * (D_SZ * 2);
    const int sw = (r & 7) << 4;
    float wn = 0.f;
#pragma unroll
    for (int i = 0; i < 8; ++i) {
      const int cc = i * 8 + j;               // 16B bf16 chunk index within row
      float4 x0 = *(const float4*)(wr + cc * 8);
      float4 x1 = *(const float4*)(wr + cc * 8 + 4);
      wn += x0.x*x0.x + x0.y*x0.y + x0.z*x0.z + x0.w*x0.w
          + x1.x*x1.x + x1.y*x1.y + x1.z*x1.z + x1.w*x1.w;
      *(bf16x8*)(wrow + ((cc * 16) ^ sw)) = cvt8(x0, x1);
    }
    wn += __shfl_xor(wn, 1, 64);
    wn += __shfl_xor(wn, 2, 64);
    wn += __shfl_xor(wn, 4, 64);
    if (j == 0) wlds[r] = wn;
  }
  __syncthreads();

  // ---- compute phase (barrier-free)
  const int l15 = lane & 15;                  // A: W-row, B/D: B-col
  const int lk  = lane >> 4;                  // k sub-chunk 0..3
  const ushort* ebase = E + (size_t)(wave * 64 + l15) * D_SZ + lk * 8;
  const char*   abase = (const char*)wtile + l15 * (D_SZ * 2);
  const int     asw   = (l15 & 7) << 4;

  f32x4 acc[4][4];
  const f32x4 z = {0.f, 0.f, 0.f, 0.f};
#pragma unroll
  for (int ci = 0; ci < 4; ++ci)
#pragma unroll
    for (int bi = 0; bi < 4; ++bi) acc[ci][bi] = z;

#pragma unroll
  for (int ks = 0; ks < 16; ++ks) {
    bf16x8 wf[4], ef[4];
    const int ko = (ks * 64 + lk * 16) ^ asw; // swizzled in-row byte offset
#pragma unroll
    for (int ci = 0; ci < 4; ++ci)
      wf[ci] = *(const bf16x8*)(abase + ci * 16 * (D_SZ * 2) + ko);
#pragma unroll
    for (int bi = 0; bi < 4; ++bi)
      ef[bi] = *(const bf16x8*)(ebase + (size_t)(bi * 16) * D_SZ + ks * 32);
#pragma unroll
    for (int ci = 0; ci < 4; ++ci)
#pragma unroll
      for (int bi = 0; bi < 4; ++bi)
        acc[ci][bi] = __builtin_amdgcn_mfma_f32_16x16x32_bf16(
            wf[ci], ef[bi], acc[ci][bi], 0, 0, 0);
  }

  // ---- epilogue: cos -> exp(64*cos-64), sum over block's 64 rows per col
  float psum[4] = {0.f, 0.f, 0.f, 0.f};
#pragma unroll
  for (int ci = 0; ci < 4; ++ci) {
#pragma unroll
    for (int r = 0; r < 4; ++r) {
      const float n2  = wlds[ci * 16 + lk * 4 + r];   // D row = ci*16+lk*4+r
      const float inv = 1.0f / fmaxf(sqrtf(n2), 1e-12f);
#pragma unroll
      for (int bi = 0; bi < 4; ++bi) {
        float c = acc[ci][bi][r] * inv;
        c = fminf(fmaxf(c, -1.0f), 1.0f);
        psum[bi] += __expf(fmaf(SCL, c, -SCL));
      }
    }
  }
#pragma unroll
  for (int bi = 0; bi < 4; ++bi) {
    psum[bi] += __shfl_xor(psum[bi], 16, 64);
    psum[bi] += __shfl_xor(psum[bi], 32, 64);
  }
  if (lk == 0) {
#pragma unroll
    for (int bi = 0; bi < 4; ++bi)
      atomicAdd(&gsum[wave * 64 + bi * 16 + l15], psum[bi]);
  }
}

// --- k3: exact f32 target logit + margin + per-row NLL.
// grid 64 blocks x 512 threads; wave handles row b = blockIdx*8 + wave.
__global__ void k_target(const float* __restrict__ W,
                         const float* __restrict__ nf32,
                         const int* __restrict__ labels,
                         const float* __restrict__ gsum,
                         float* __restrict__ nll) {   // nll[0]=sum, nll[1]=count
  const int wave = threadIdx.x >> 6;
  const int lane = threadIdx.x & 63;
  const int b = blockIdx.x * 8 + wave;
  const int lab = labels[b];
  const bool valid = (lab >= 0);
  const int slab = valid ? lab : 0;
  const float* wr = W    + (size_t)slab * D_SZ;
  const float* er = nf32 + (size_t)b    * D_SZ;
  float dot = 0.f, wn2 = 0.f;
#pragma unroll
  for (int i = 0; i < 2; ++i) {
    const int d = i * 256 + lane * 4;
    float4 w4 = *(const float4*)(wr + d);
    float4 e4 = *(const float4*)(er + d);
    dot += w4.x*e4.x + w4.y*e4.y + w4.z*e4.z + w4.w*e4.w;
    wn2 += w4.x*w4.x + w4.y*w4.y + w4.z*w4.z + w4.w*w4.w;
  }
#pragma unroll
  for (int off = 32; off; off >>= 1) {
    dot += __shfl_xor(dot, off, 64);
    wn2 += __shfl_xor(wn2, off, 64);
  }
  if (lane == 0 && valid) {
    const float inv  = 1.0f / fmaxf(sqrtf(wn2), 1e-12f);
    float cost = fminf(fmaxf(dot * inv, -1.0f), 1.0f);      // clamped cosine
    const float th   = acosf(fminf(fmaxf(cost, -1.0f + 1e-7f), 1.0f - 1e-7f));
    const float newt = cosf(th + MRG);
    // swap target term in the fixed-shift (max=64) denominator
    const float sum  = gsum[b] - expf(fmaf(SCL, cost, -SCL))
                               + expf(fmaf(SCL, newt, -SCL));
    const float lse  = logf(sum) + SCL;
    atomicAdd(&nll[0], lse - SCL * newt);
    atomicAdd(&nll[1], 1.0f);
  }
}

__global__ void k_final(const float* __restrict__ nll, float* __restrict__ out) {
  out[0] = nll[0] / fmaxf(nll[1], 1.0f);
}

// ---------------------------------------------------------------------------
extern "C" void kernel_launch(void* const* d_in, const int* in_sizes, int n_in,
                              void* d_out, int out_size, void* d_ws, size_t ws_size,
                              hipStream_t stream) {
  const float* emb    = (const float*)d_in[0];
  const int*   labels = (const int*)  d_in[1];
  const float* W      = (const float*)d_in[2];
  float* out = (float*)d_out;

  // ws layout: [0,1MB) norm_emb f32 | [1MB,1.5MB) norm_emb bf16
  //            | gsum[512] | nll[2]
  char* ws = (char*)d_ws;
  float*  nf32 = (float*)ws;
  ushort* nbf  = (ushort*)(ws + (1u << 20));
  float*  gsum = (float*)(ws + (1u << 20) + (1u << 19));
  float*  nll  = gsum + B_SZ;

  hipMemsetAsync(gsum, 0, (B_SZ + 2) * sizeof(float), stream);
  k_norm_emb<<<B_SZ / 4, 256, 0, stream>>>(emb, nf32, nbf);
  k_gemm_lse<<<C_SZ / BM, 512, 0, stream>>>(W, nbf, gsum);
  k_target<<<B_SZ / 8, 512, 0, stream>>>(W, nf32, labels, gsum, nll);
  k_final<<<1, 1, 0, stream>>>(nll, out);
}